// Round 5
// baseline (198.835 us; speedup 1.0000x reference)
//
#include <hip/hip_runtime.h>
#include <hip/hip_bf16.h>
#include <math.h>

#define Bn 8
#define Cn 1152
#define Hn 32
#define Wn 32
#define Nn 1024  // Hn*Wn

typedef short short8 __attribute__((ext_vector_type(8)));
typedef float f32x4 __attribute__((ext_vector_type(4)));

// Softmax state. Fully overwritten every call.
__device__ float g_rmax[Bn * Nn];
__device__ float g_rsuminv[Bn * Nn];
__device__ float g_csum_part[Bn * 8 * Nn];  // per-(b, i-tile) partial column sums
// bf16 operands for the MFMA GEMM. Fully overwritten every call.
__device__ unsigned short g_A[(size_t)Bn * Nn * Nn];   // E[b][i][j] = exp(w) (unnormalized)
__device__ unsigned short g_fb[(size_t)Bn * Cn * Nn];  // f_src[b][c][j] / csum[b][j] in bf16

__device__ inline unsigned short f2bf(float x) {
    __hip_bfloat16 h = __float2bfloat16(x);
    unsigned short u;
    __builtin_memcpy(&u, &h, 2);
    return u;
}

__device__ inline void inv3(const float* M, float* o) {
    float a = M[0], b = M[1], c = M[2];
    float d = M[3], e = M[4], f = M[5];
    float g = M[6], h = M[7], i = M[8];
    float A0 = (e * i - f * h);
    float A1 = -(d * i - f * g);
    float A2 = (d * h - e * g);
    float det = a * A0 + b * A1 + c * A2;
    float inv = 1.0f / det;
    o[0] = A0 * inv;
    o[1] = -(b * i - c * h) * inv;
    o[2] = (b * f - c * e) * inv;
    o[3] = A1 * inv;
    o[4] = (a * i - c * g) * inv;
    o[5] = -(a * f - c * d) * inv;
    o[6] = A2 * inv;
    o[7] = -(a * h - b * g) * inv;
    o[8] = (a * e - b * d) * inv;
}

__device__ inline void mm3(const float* X, const float* Y, float* Z) {
    for (int r = 0; r < 3; r++)
        for (int c = 0; c < 3; c++)
            Z[r * 3 + c] = X[r * 3 + 0] * Y[0 * 3 + c] + X[r * 3 + 1] * Y[1 * 3 + c] +
                           X[r * 3 + 2] * Y[2 * 3 + c];
}

// F = inv(K2^T) skew(t) R inv(K1).  SVD in the reference is a rank-2 no-op
// (skew(t)@R has singular values (|t|,|t|,0)).  ~200 uniform scalar ops —
// recomputed per block instead of a separate setup dispatch.
__device__ inline void computeF(const float* K1, const float* K2, const float* R,
                                const float* t, int b, float* F) {
    float t0 = t[b * 3 + 0], t1 = t[b * 3 + 1], t2 = t[b * 3 + 2];
    float S[9] = {0.0f, -t2, t1, t2, 0.0f, -t0, -t1, t0, 0.0f};
    float E[9];
    mm3(S, &R[b * 9], E);
    float iK1[9], iK2[9];
    inv3(&K1[b * 9], iK1);
    inv3(&K2[b * 9], iK2);
    float iK2T[9] = {iK2[0], iK2[3], iK2[6], iK2[1], iK2[4], iK2[7], iK2[2], iK2[5], iK2[8]};
    float T[9];
    mm3(iK2T, E, T);
    mm3(T, iK1, F);
}

// Per-j epipolar line params from F
__device__ inline void lineparams(const float* F, int j, float& dy, float& y0, float& invn) {
    float ix = (float)(j >> 5);
    float iy = (float)(j & 31);
    float l0 = F[0] * ix + F[1] * iy + F[2];
    float l1 = F[3] * ix + F[4] * iy + F[5];
    float l2 = F[6] * ix + F[7] * iy + F[8];
    l0 = l0 / l2;
    l1 = l1 / l2;
    y0 = -1.0f / l1;
    float y1 = -(1.0f + l0 * 32.0f) / l1;
    dy = y0 - y1;
    invn = 1.0f / sqrtf(1024.0f + dy * dy);
}

__device__ inline float zval(float ix, float iy, float dy, float y0, float invn) {
    float d = fabsf(ix * dy + 32.0f * (iy - y0)) * invn;
    return 5.0f * (d - 0.1f);
}

// Row softmax stats (over j), one wave per row i. Grid 2048: lin&7 = b = XCD.
__global__ void rowstats_kernel(const float* __restrict__ K1, const float* __restrict__ K2,
                                const float* __restrict__ R, const float* __restrict__ t) {
    int lin = blockIdx.x;
    int b = lin & 7;
    int seg = lin >> 3;  // 0..255
    float F[9];
    computeF(K1, K2, R, t, b, F);
    int wv = threadIdx.x >> 6;
    int lane = threadIdx.x & 63;
    int i = seg * 4 + wv;
    float ix = (float)(i >> 5), iy = (float)(i & 31);
    float z[16];
    float m = -INFINITY;
#pragma unroll
    for (int k = 0; k < 16; k++) {
        int j = lane + k * 64;
        float dy, y0, invn;
        lineparams(F, j, dy, y0, invn);
        z[k] = zval(ix, iy, dy, y0, invn);
        m = fmaxf(m, z[k]);
    }
#pragma unroll
    for (int o = 32; o > 0; o >>= 1) m = fmaxf(m, __shfl_xor(m, o, 64));
    float s = 0.0f;
#pragma unroll
    for (int k = 0; k < 16; k++) s += __expf(z[k] - m);
#pragma unroll
    for (int o = 32; o > 0; o >>= 1) s += __shfl_xor(s, o, 64);
    if (lane == 0) {
        g_rmax[b * Nn + i] = m;
        g_rsuminv[b * Nn + i] = 1.0f / s;
    }
}

// Fused column pass: E = exp(1 - rowsoftmax) as bf16 + per-(b,i-tile) partial column
// sums (no atomics). w in (0,1) so no max-subtraction needed for stability.
// Grid 1024: lin&7 = b = XCD; jt = 16 tiles of 64 j, it = 8 tiles of 128 i.
__global__ void colE_kernel(const float* __restrict__ K1, const float* __restrict__ K2,
                            const float* __restrict__ R, const float* __restrict__ t) {
    int lin = blockIdx.x;
    int b = lin & 7;
    int r = lin >> 3;
    int jt = r & 15;
    int it = r >> 4;
    float F[9];
    computeF(K1, K2, R, t, b, F);
    int tt = threadIdx.x;
    int jloc = tt & 63;
    int ig = tt >> 6;  // wave index 0..3
    int j = jt * 64 + jloc;
    int base = b * Nn;
    float dy, y0, invn;
    lineparams(F, j, dy, y0, invn);
    float csump = 0.0f;
#pragma unroll 4
    for (int k = 0; k < 32; k++) {
        int i = it * 128 + ig * 32 + k;  // wave-uniform
        float rmax = g_rmax[base + i];
        float rsi = g_rsuminv[base + i];
        float ix = (float)(i >> 5), iy = (float)(i & 31);
        float z = zval(ix, iy, dy, y0, invn);
        float s1 = __expf(z - rmax) * rsi;
        float E = __expf(1.0f - s1);
        csump += E;
        g_A[((size_t)base + i) * Nn + j] = f2bf(E);
    }
    __shared__ float red[4][64];
    red[ig][jloc] = csump;
    __syncthreads();
    if (ig == 0) {
        float s = red[0][jloc] + red[1][jloc] + red[2][jloc] + red[3][jloc];
        g_csum_part[(b * 8 + it) * Nn + j] = s;
    }
}

// f_src fp32 -> bf16 scaled by 1/csum[b][j] (column-softmax denominator folded into
// the B operand). Grid 9216: lin&7 = b = XCD, lin>>3 = channel c.
__global__ void convert_fsrc_kernel(const float* __restrict__ f) {
    int lin = blockIdx.x;
    int b = lin & 7;
    int c = lin >> 3;
    int j = threadIdx.x * 4;
    float4 cs = *(const float4*)&g_csum_part[(b * 8 + 0) * Nn + j];
#pragma unroll
    for (int it = 1; it < 8; it++) {
        float4 p = *(const float4*)&g_csum_part[(b * 8 + it) * Nn + j];
        cs.x += p.x; cs.y += p.y; cs.z += p.z; cs.w += p.w;
    }
    size_t off = ((size_t)b * Cn + c) * Nn + j;
    float4 v = *(const float4*)(f + off);
    ushort4 u;
    u.x = f2bf(v.x / cs.x);
    u.y = f2bf(v.y / cs.y);
    u.z = f2bf(v.z / cs.z);
    u.w = f2bf(v.w / cs.w);
    *(ushort4*)&g_fb[off] = u;
}

// out[b,i,c] = sum_j E[b,i,j] * fb_scaled[b,c,j]  — both operands K(j)-contiguous.
// 128(i) x 128(c) tile, BK=32, 4 waves x (4x4) mfma_16x16x32, DOUBLE-BUFFERED LDS:
// next tile's global_load_lds issued after the barrier, in flight during compute.
// 1D grid, lin&7 = b = XCD: per-batch A (2 MB) + fb (2.36 MB) stay in that XCD's L2.
#define BM 128
#define BNc 128
#define BK 32

__launch_bounds__(256) __global__ void gemm_kernel(float* __restrict__ out) {
    __shared__ unsigned short As[2][BM * BK];
    __shared__ unsigned short Bs[2][BNc * BK];
    int lin = blockIdx.x;
    int b = lin & 7;
    int s = lin >> 3;  // 0..71
    int it = s / 9;
    int ct = s - it * 9;
    int i0 = it * BM;
    int c0 = ct * BNc;
    int t = threadIdx.x;
    int w = t >> 6, L = t & 63;
    int wm = w >> 1, wn = w & 1;
    const unsigned short* Ab = g_A + (size_t)b * Nn * Nn + (size_t)i0 * Nn;
    const unsigned short* Fb = g_fb + (size_t)b * Cn * Nn + (size_t)c0 * Nn;

    // stage K-tile kt into buffer p (4 x 16B global_load_lds per thread)
    auto stage = [&](int p, int kt) {
#pragma unroll
        for (int h = 0; h < 2; h++) {
            int chunk = (h * 4 + w) * 64 + L;       // 0..511, 16B each
            int rr = chunk >> 2;                    // tile row 0..127
            int gq = (chunk & 3) ^ ((rr >> 1) & 3); // swizzled global k-quad
            const unsigned short* ga = Ab + (size_t)rr * Nn + kt + gq * 8;
            const unsigned short* gb = Fb + (size_t)rr * Nn + kt + gq * 8;
            __builtin_amdgcn_global_load_lds(
                (const __attribute__((address_space(1))) unsigned int*)ga,
                (__attribute__((address_space(3))) unsigned int*)(As[p] + chunk * 8), 16, 0, 0);
            __builtin_amdgcn_global_load_lds(
                (const __attribute__((address_space(1))) unsigned int*)gb,
                (__attribute__((address_space(3))) unsigned int*)(Bs[p] + chunk * 8), 16, 0, 0);
        }
    };

    f32x4 acc[4][4] = {};
    int lrow = L & 15, quad = L >> 4;
    stage(0, 0);
    for (int kt = 0; kt < Nn; kt += BK) {
        int p = (kt >> 5) & 1;
        __syncthreads();  // vmcnt(0): buffer p staged; prev compute (buf 1-p) retired
        if (kt + BK < Nn) stage(1 - p, kt + BK);  // overlaps with compute below
        short8 af[4], bf[4];
#pragma unroll
        for (int mt = 0; mt < 4; mt++) {
            int rr = wm * 64 + mt * 16 + lrow;
            int q = quad ^ ((rr >> 1) & 3);
            af[mt] = *(const short8*)(As[p] + rr * BK + q * 8);
        }
#pragma unroll
        for (int nt = 0; nt < 4; nt++) {
            int rr = wn * 64 + nt * 16 + lrow;
            int q = quad ^ ((rr >> 1) & 3);
            bf[nt] = *(const short8*)(Bs[p] + rr * BK + q * 8);
        }
#pragma unroll
        for (int mt = 0; mt < 4; mt++)
#pragma unroll
            for (int nt = 0; nt < 4; nt++)
                acc[mt][nt] =
                    __builtin_amdgcn_mfma_f32_16x16x32_bf16(af[mt], bf[nt], acc[mt][nt], 0, 0, 0);
    }
    // Epilogue: D col=lane&15, row=(lane>>4)*4+reg  [m89-verified]
#pragma unroll
    for (int mt = 0; mt < 4; mt++)
#pragma unroll
        for (int rg = 0; rg < 4; rg++) {
            int i = i0 + wm * 64 + mt * 16 + quad * 4 + rg;
            float* orow = out + ((size_t)b * Nn + i) * Cn + c0 + wn * 64;
#pragma unroll
            for (int nt = 0; nt < 4; nt++) orow[nt * 16 + quad * 0 + (L & 15)] = acc[mt][nt][rg];
        }
}

extern "C" void kernel_launch(void* const* d_in, const int* in_sizes, int n_in,
                              void* d_out, int out_size, void* d_ws, size_t ws_size,
                              hipStream_t stream) {
    (void)in_sizes; (void)n_in; (void)d_ws; (void)ws_size; (void)out_size;
    const float* f_src = (const float*)d_in[1];  // d_in[0] = f_tar unused by reference
    const float* K1 = (const float*)d_in[2];
    const float* K2 = (const float*)d_in[3];
    const float* R = (const float*)d_in[4];
    const float* t = (const float*)d_in[5];
    float* out = (float*)d_out;

    rowstats_kernel<<<dim3(2048), dim3(256), 0, stream>>>(K1, K2, R, t);
    colE_kernel<<<dim3(1024), dim3(256), 0, stream>>>(K1, K2, R, t);
    convert_fsrc_kernel<<<dim3(Bn * Cn), dim3(256), 0, stream>>>(f_src);
    gemm_kernel<<<dim3(Bn * (Nn / BM) * (Cn / BNc)), dim3(256), 0, stream>>>(out);
}

// Round 6
// 171.421 us; speedup vs baseline: 1.1599x; 1.1599x over previous
//
#include <hip/hip_runtime.h>
#include <hip/hip_bf16.h>
#include <math.h>

#define Bn 8
#define Cn 1152
#define Hn 32
#define Wn 32
#define Nn 1024  // Hn*Wn

typedef short short8 __attribute__((ext_vector_type(8)));
typedef float f32x4 __attribute__((ext_vector_type(4)));

// Softmax state. Fully overwritten every call.
__device__ float g_rmax[Bn * Nn];
__device__ float g_rsuminv[Bn * Nn];
__device__ float g_csum_part[Bn * 8 * Nn];  // per-(b, i-tile) partial column sums
// bf16 operands for the MFMA GEMM. Fully overwritten every call.
__device__ unsigned short g_A[(size_t)Bn * Nn * Nn];   // E[b][i][j] = exp(w) (unnormalized)
__device__ unsigned short g_fb[(size_t)Bn * Cn * Nn];  // f_src[b][c][j] / csum[b][j] in bf16

__device__ inline unsigned short f2bf(float x) {
    __hip_bfloat16 h = __float2bfloat16(x);
    unsigned short u;
    __builtin_memcpy(&u, &h, 2);
    return u;
}

__device__ inline void inv3(const float* M, float* o) {
    float a = M[0], b = M[1], c = M[2];
    float d = M[3], e = M[4], f = M[5];
    float g = M[6], h = M[7], i = M[8];
    float A0 = (e * i - f * h);
    float A1 = -(d * i - f * g);
    float A2 = (d * h - e * g);
    float det = a * A0 + b * A1 + c * A2;
    float inv = 1.0f / det;
    o[0] = A0 * inv;
    o[1] = -(b * i - c * h) * inv;
    o[2] = (b * f - c * e) * inv;
    o[3] = A1 * inv;
    o[4] = (a * i - c * g) * inv;
    o[5] = -(a * f - c * d) * inv;
    o[6] = A2 * inv;
    o[7] = -(a * h - b * g) * inv;
    o[8] = (a * e - b * d) * inv;
}

__device__ inline void mm3(const float* X, const float* Y, float* Z) {
    for (int r = 0; r < 3; r++)
        for (int c = 0; c < 3; c++)
            Z[r * 3 + c] = X[r * 3 + 0] * Y[0 * 3 + c] + X[r * 3 + 1] * Y[1 * 3 + c] +
                           X[r * 3 + 2] * Y[2 * 3 + c];
}

// F = inv(K2^T) skew(t) R inv(K1).  SVD in the reference is a rank-2 no-op
// (skew(t)@R has singular values (|t|,|t|,0)). Run by thread 0 of each block.
__device__ inline void computeF(const float* K1, const float* K2, const float* R,
                                const float* t, int b, float* F) {
    float t0 = t[b * 3 + 0], t1 = t[b * 3 + 1], t2 = t[b * 3 + 2];
    float S[9] = {0.0f, -t2, t1, t2, 0.0f, -t0, -t1, t0, 0.0f};
    float E[9];
    mm3(S, &R[b * 9], E);
    float iK1[9], iK2[9];
    inv3(&K1[b * 9], iK1);
    inv3(&K2[b * 9], iK2);
    float iK2T[9] = {iK2[0], iK2[3], iK2[6], iK2[1], iK2[4], iK2[7], iK2[2], iK2[5], iK2[8]};
    float T[9];
    mm3(iK2T, E, T);
    mm3(T, iK1, F);
}

// Per-j coefficients so that z_ij = |ix*P + iy*Q - R| - 0.5  (== 5*(d_epi - 0.1))
__device__ inline float4 zcoef(const float* F, int j) {
    float jx = (float)(j >> 5);
    float jy = (float)(j & 31);
    float l0 = F[0] * jx + F[1] * jy + F[2];
    float l1 = F[3] * jx + F[4] * jy + F[5];
    float l2 = F[6] * jx + F[7] * jy + F[8];
    l0 = l0 / l2;
    l1 = l1 / l2;
    float y0 = -1.0f / l1;
    float y1 = -(1.0f + l0 * 32.0f) / l1;
    float dy = y0 - y1;
    float invn = 1.0f / sqrtf(1024.0f + dy * dy);
    return make_float4(5.0f * dy * invn, 160.0f * invn, 160.0f * y0 * invn, 0.0f);
}

// Row softmax stats (over j), one wave per row i. Grid 2048: lin&7 = b = XCD.
__global__ void rowstats_kernel(const float* __restrict__ K1, const float* __restrict__ K2,
                                const float* __restrict__ R, const float* __restrict__ t) {
    __shared__ float Fs[9];
    __shared__ float4 prm[Nn];
    int lin = blockIdx.x;
    int b = lin & 7;
    int seg = lin >> 3;  // 0..255
    if (threadIdx.x == 0) computeF(K1, K2, R, t, b, Fs);
    __syncthreads();
    // phase 1: per-j coefficients into LDS (4 per thread)
#pragma unroll
    for (int u = 0; u < 4; u++) {
        int j = threadIdx.x * 4 + u;
        prm[j] = zcoef(Fs, j);
    }
    __syncthreads();
    // phase 2: wave wv owns row i = seg*4+wv
    int wv = threadIdx.x >> 6;
    int lane = threadIdx.x & 63;
    int i = seg * 4 + wv;
    float ix = (float)(i >> 5), iy = (float)(i & 31);
    float z[16];
    float m = -INFINITY;
#pragma unroll
    for (int k = 0; k < 16; k++) {
        float4 p = prm[lane + k * 64];
        z[k] = fabsf(fmaf(ix, p.x, fmaf(iy, p.y, -p.z))) - 0.5f;
        m = fmaxf(m, z[k]);
    }
#pragma unroll
    for (int o = 32; o > 0; o >>= 1) m = fmaxf(m, __shfl_xor(m, o, 64));
    float s = 0.0f;
#pragma unroll
    for (int k = 0; k < 16; k++) s += __expf(z[k] - m);
#pragma unroll
    for (int o = 32; o > 0; o >>= 1) s += __shfl_xor(s, o, 64);
    if (lane == 0) {
        g_rmax[b * Nn + i] = m;
        g_rsuminv[b * Nn + i] = 1.0f / s;
    }
}

// Fused column pass: E = exp(1 - rowsoftmax) as bf16 (ushort4 stores) + per-(b,it)
// partial column sums. w in (0,1) so no max-subtraction needed for stability.
// Grid 1024: lin&7 = b = XCD; jt = 16 tiles of 64 j, it = 8 tiles of 128 i.
__global__ void colE_kernel(const float* __restrict__ K1, const float* __restrict__ K2,
                            const float* __restrict__ R, const float* __restrict__ t) {
    __shared__ float Fs[9];
    __shared__ float rm[128], rs[128];
    __shared__ float4 red[16][16];
    int lin = blockIdx.x;
    int b = lin & 7;
    int r = lin >> 3;
    int jt = r & 15;
    int it = r >> 4;
    int tt = threadIdx.x;
    if (tt < 128) {
        rm[tt] = g_rmax[b * Nn + it * 128 + tt];
        rs[tt] = g_rsuminv[b * Nn + it * 128 + tt];
    }
    if (tt == 0) computeF(K1, K2, R, t, b, Fs);
    __syncthreads();
    int tcol = tt & 15, trow = tt >> 4;
    int j0 = jt * 64 + tcol * 4;
    float4 p0 = zcoef(Fs, j0 + 0);
    float4 p1 = zcoef(Fs, j0 + 1);
    float4 p2 = zcoef(Fs, j0 + 2);
    float4 p3 = zcoef(Fs, j0 + 3);
    float4 csum = make_float4(0.f, 0.f, 0.f, 0.f);
#pragma unroll
    for (int k = 0; k < 8; k++) {
        int il = trow + k * 16;  // 0..127, each once
        float rmax = rm[il], rsi = rs[il];
        int i = it * 128 + il;
        float ix = (float)(i >> 5), iy = (float)(i & 31);
        float z0 = fabsf(fmaf(ix, p0.x, fmaf(iy, p0.y, -p0.z))) - 0.5f;
        float z1 = fabsf(fmaf(ix, p1.x, fmaf(iy, p1.y, -p1.z))) - 0.5f;
        float z2 = fabsf(fmaf(ix, p2.x, fmaf(iy, p2.y, -p2.z))) - 0.5f;
        float z3 = fabsf(fmaf(ix, p3.x, fmaf(iy, p3.y, -p3.z))) - 0.5f;
        float E0 = __expf(1.0f - __expf(z0 - rmax) * rsi);
        float E1 = __expf(1.0f - __expf(z1 - rmax) * rsi);
        float E2 = __expf(1.0f - __expf(z2 - rmax) * rsi);
        float E3 = __expf(1.0f - __expf(z3 - rmax) * rsi);
        csum.x += E0; csum.y += E1; csum.z += E2; csum.w += E3;
        ushort4 u;
        u.x = f2bf(E0); u.y = f2bf(E1); u.z = f2bf(E2); u.w = f2bf(E3);
        *(ushort4*)&g_A[((size_t)b * Nn + i) * Nn + j0] = u;
    }
    red[trow][tcol] = csum;
    __syncthreads();
    if (tt < 16) {
        float4 s = red[0][tt];
#pragma unroll
        for (int q = 1; q < 16; q++) {
            float4 p = red[q][tt];
            s.x += p.x; s.y += p.y; s.z += p.z; s.w += p.w;
        }
        *(float4*)&g_csum_part[(b * 8 + it) * Nn + jt * 64 + tt * 4] = s;
    }
}

// f_src fp32 -> bf16 scaled by 1/csum[b][j], 8 channels per block (csum loaded once).
// Grid 1152: lin&7 = b = XCD, cg = lin>>3 (0..143) = 8-channel group.
__global__ void convert_fsrc_kernel(const float* __restrict__ f) {
    int lin = blockIdx.x;
    int b = lin & 7;
    int cg = lin >> 3;
    int j0 = threadIdx.x * 4;
    float4 cs = *(const float4*)&g_csum_part[(b * 8 + 0) * Nn + j0];
#pragma unroll
    for (int it = 1; it < 8; it++) {
        float4 p = *(const float4*)&g_csum_part[(b * 8 + it) * Nn + j0];
        cs.x += p.x; cs.y += p.y; cs.z += p.z; cs.w += p.w;
    }
    float4 inv = make_float4(1.0f / cs.x, 1.0f / cs.y, 1.0f / cs.z, 1.0f / cs.w);
#pragma unroll
    for (int c8 = 0; c8 < 8; c8++) {
        int c = cg * 8 + c8;
        size_t off = ((size_t)b * Cn + c) * Nn + j0;
        float4 v = *(const float4*)(f + off);
        ushort4 u;
        u.x = f2bf(v.x * inv.x);
        u.y = f2bf(v.y * inv.y);
        u.z = f2bf(v.z * inv.z);
        u.w = f2bf(v.w * inv.w);
        *(ushort4*)&g_fb[off] = u;
    }
}

// out[b,i,c] = sum_j E[b,i,j] * fb_scaled[b,c,j]  — both operands K(j)-contiguous.
// 128(i) x 64(c) block-tile, 128 threads = 2 waves, each wave the proven 64x64 tile
// (4x4 mfma_16x16x32). Double-buffered LDS; grid 1152 = 4.5 blocks/CU for cross-block
// latency hiding. lin&7 = b = XCD: per-batch A (2 MB) + fb (2.36 MB) stay in L2.
#define BM 128
#define BNc 64
#define BK 32

__launch_bounds__(128) __global__ void gemm_kernel(float* __restrict__ out) {
    __shared__ unsigned short As[2][BM * BK];  // 8 KB each
    __shared__ unsigned short Bs[2][BNc * BK]; // 4 KB each
    int lin = blockIdx.x;
    int b = lin & 7;
    int s = lin >> 3;  // 0..143
    int it = s & 7;
    int ct = s >> 3;   // 0..17
    int i0 = it * BM;
    int c0 = ct * BNc;
    int t = threadIdx.x;
    int w = t >> 6, L = t & 63;  // w = i-half
    const unsigned short* Ab = g_A + (size_t)b * Nn * Nn + (size_t)i0 * Nn;
    const unsigned short* Fb = g_fb + (size_t)b * Cn * Nn + (size_t)c0 * Nn;

    // stage K-tile kt into buffer p: A = 256 chunks, B = 128 chunks, 16B each
    auto stage = [&](int p, int kt) {
#pragma unroll
        for (int h = 0; h < 2; h++) {
            int chunk = h * 128 + t;                 // 0..255
            int rr = chunk >> 2;                     // A row 0..127
            int gq = (chunk & 3) ^ ((rr >> 1) & 3);  // swizzled global k-quad
            const unsigned short* ga = Ab + (size_t)rr * Nn + kt + gq * 8;
            __builtin_amdgcn_global_load_lds(
                (const __attribute__((address_space(1))) unsigned int*)ga,
                (__attribute__((address_space(3))) unsigned int*)(As[p] + chunk * 8), 16, 0, 0);
        }
        {
            int chunk = t;                           // 0..127
            int rr = chunk >> 2;                     // B row (c) 0..63... wait 128/4=32
            int gq = (chunk & 3) ^ ((rr >> 1) & 3);
            const unsigned short* gb = Fb + (size_t)rr * Nn + kt + gq * 8;
            __builtin_amdgcn_global_load_lds(
                (const __attribute__((address_space(1))) unsigned int*)gb,
                (__attribute__((address_space(3))) unsigned int*)(Bs[p] + chunk * 8), 16, 0, 0);
        }
    };
    // NOTE: B tile is 64 rows x 32 k = 2048 shorts = 128 chunks; chunk>>2 gives rows
    // 0..31 for chunks 0..127? No: 128 chunks / 4 per row = 32 rows. WRONG — fixed:
    // B needs 64 rows x 4 quads = 256 half-chunks... Correct mapping below in stageB.

    f32x4 acc[4][4] = {};
    int lrow = L & 15, quad = L >> 4;
    // correct B staging: 64 rows x 32k = 4KB = 256 x 16B? 64*32*2B = 4096B = 256 chunks
    // of 16B is wrong (256*16 = 4096 ✓ ... 4096 B / 16 B = 256 chunks). Both A (8KB=512?)
    // A: 128*32*2 = 8192 B = 512 chunks. Redo staging cleanly:
    auto stage2 = [&](int p, int kt) {
        // A: 512 x 16B chunks, 4 per thread
#pragma unroll
        for (int h = 0; h < 4; h++) {
            int chunk = h * 128 + t;                 // 0..511
            int rr = chunk >> 2;                     // row 0..127
            int gq = (chunk & 3) ^ ((rr >> 1) & 3);
            const unsigned short* ga = Ab + (size_t)rr * Nn + kt + gq * 8;
            __builtin_amdgcn_global_load_lds(
                (const __attribute__((address_space(1))) unsigned int*)ga,
                (__attribute__((address_space(3))) unsigned int*)(As[p] + chunk * 8), 16, 0, 0);
        }
        // B: 256 x 16B chunks, 2 per thread
#pragma unroll
        for (int h = 0; h < 2; h++) {
            int chunk = h * 128 + t;                 // 0..255
            int rr = chunk >> 2;                     // row 0..63
            int gq = (chunk & 3) ^ ((rr >> 1) & 3);
            const unsigned short* gb = Fb + (size_t)rr * Nn + kt + gq * 8;
            __builtin_amdgcn_global_load_lds(
                (const __attribute__((address_space(1))) unsigned int*)gb,
                (__attribute__((address_space(3))) unsigned int*)(Bs[p] + chunk * 8), 16, 0, 0);
        }
    };
    (void)stage;

    stage2(0, 0);
    for (int kt = 0; kt < Nn; kt += BK) {
        int p = (kt >> 5) & 1;
        __syncthreads();  // vmcnt(0): buffer p staged; prev compute retired
        if (kt + BK < Nn) stage2(1 - p, kt + BK);  // in flight during compute below
        short8 af[4], bf[4];
#pragma unroll
        for (int mt = 0; mt < 4; mt++) {
            int rr = w * 64 + mt * 16 + lrow;
            int q = quad ^ ((rr >> 1) & 3);
            af[mt] = *(const short8*)(As[p] + rr * BK + q * 8);
        }
#pragma unroll
        for (int nt = 0; nt < 4; nt++) {
            int cc = nt * 16 + lrow;
            int q = quad ^ ((cc >> 1) & 3);
            bf[nt] = *(const short8*)(Bs[p] + cc * BK + q * 8);
        }
#pragma unroll
        for (int mt = 0; mt < 4; mt++)
#pragma unroll
            for (int nt = 0; nt < 4; nt++)
                acc[mt][nt] =
                    __builtin_amdgcn_mfma_f32_16x16x32_bf16(af[mt], bf[nt], acc[mt][nt], 0, 0, 0);
    }
    // Epilogue: D col=lane&15, row=(lane>>4)*4+reg  [m89-verified]
    int col = L & 15;
#pragma unroll
    for (int mt = 0; mt < 4; mt++)
#pragma unroll
        for (int rg = 0; rg < 4; rg++) {
            int i = i0 + w * 64 + mt * 16 + quad * 4 + rg;
            float* orow = out + ((size_t)b * Nn + i) * Cn + c0;
#pragma unroll
            for (int nt = 0; nt < 4; nt++) orow[nt * 16 + col] = acc[mt][nt][rg];
        }
}

extern "C" void kernel_launch(void* const* d_in, const int* in_sizes, int n_in,
                              void* d_out, int out_size, void* d_ws, size_t ws_size,
                              hipStream_t stream) {
    (void)in_sizes; (void)n_in; (void)d_ws; (void)ws_size; (void)out_size;
    const float* f_src = (const float*)d_in[1];  // d_in[0] = f_tar unused by reference
    const float* K1 = (const float*)d_in[2];
    const float* K2 = (const float*)d_in[3];
    const float* R = (const float*)d_in[4];
    const float* t = (const float*)d_in[5];
    float* out = (float*)d_out;

    rowstats_kernel<<<dim3(2048), dim3(256), 0, stream>>>(K1, K2, R, t);
    colE_kernel<<<dim3(1024), dim3(256), 0, stream>>>(K1, K2, R, t);
    convert_fsrc_kernel<<<dim3(Bn * Cn / 8), dim3(256), 0, stream>>>(f_src);
    gemm_kernel<<<dim3(Bn * (Nn / BM) * (Cn / BNc)), dim3(128), 0, stream>>>(out);
}